// Round 7
// baseline (3077.727 us; speedup 1.0000x reference)
//
#include <hip/hip_runtime.h>
#include <math.h>
#include <stdint.h>

// ============================================================================
// TopDownNet via split-f16 MFMA, R11: 32x32x16 MFMA + weight prefetch.
// R9 (2407us, best): of-eighth split, MfmaUtil 57%. R10 (of x sample split)
// REGRESSED (+445us): doubling per-wave weight loads exposed ~200cyc L2-hit
// latency per chunk (loads can't issue past unpiped loop boundary). Lesson:
// weight-load latency, not LDS, is the secondary constraint after MFMA.
// R11 keeps R9's decomposition (wave wu owns of [32wu,32wu+32) x 64 samples):
//  - mfma_f32_32x32x16_f16: 4096 FLOP/cyc vs 3378 (16x16) -> MFMA demand
//    1.30 -> 1.08 ms; MFMA inst count halves. acc = 2 x f32x16 x2 = 64 regs.
//  - 2-deep manual weight prefetch (named A/B bufs, compile-time indexed):
//    chunk c+1 weights load during chunk c's 12 MFMAs -> latency covered.
//  - weight/LDS bytes per chunk unchanged vs R9 (4 dwordx4 + 8 ds_read_b128).
// D layout 32x32 (m74/m101): col=l&31, row=(r&3)+8*(r>>2)+4*(l>>5).
// A: row(of)=l&31, k=(l>>5)*8+i ; B: col(sample)=l&31, same k.
// Split math (validated R5-R10, absmax 3.8e-6): x = xh + xl*2^-11, w likewise;
//   acc1 += xh*wh ; acc2 += xh*wl + xl*wh ; result = acc1 + acc2/2048.
// ============================================================================

typedef _Float16 half8 __attribute__((ext_vector_type(8)));
typedef __fp16 fp16x2 __attribute__((ext_vector_type(2)));  // cvt_pkrtz native
typedef float f32x16 __attribute__((ext_vector_type(16)));

constexpr int KS = 10;
constexpr int RSTR = 584;  // f16/row: 288 hi + 288 lo + 8 pad
constexpr float SPLIT_S = 2048.f;
constexpr float SPLIT_INV = 1.f / 2048.f;

// W^T fragment streams for 32x32: frag = 32 of x 16 k, 64 lanes x 8 f16 (1KB).
// Within layer: frag f = kc*8 + ot (kc = k/16, ot = of/32).
// Layer bases (frags): O1 0, M1 144, O2 288, M2 416, M3 544 (total 672).
__device__ __align__(16) _Float16 g_Wh[672 * 512];
__device__ __align__(16) _Float16 g_Wl[672 * 512];
// M1 park: 2048 blocks x 8 waves x 8 uint4 x 64 lanes (wave-private slots).
__device__ __align__(16) uint4 g_park[2048u * 8u * 8u * 64u];

__global__ void prep_w(const float* __restrict__ O1w, const float* __restrict__ M1w,
                       const float* __restrict__ O2w, const float* __restrict__ M2w,
                       const float* __restrict__ M3w) {
  const int bid = blockIdx.x, l = threadIdx.x;
  const float* W; int Ksrc, f;
  if (bid < 144)      { W = O1w; Ksrc = 270; f = bid; }
  else if (bid < 288) { W = M1w; Ksrc = 270; f = bid - 144; }
  else if (bid < 416) { W = O2w; Ksrc = 256; f = bid - 288; }
  else if (bid < 544) { W = M2w; Ksrc = 256; f = bid - 416; }
  else                { W = M3w; Ksrc = 256; f = bid - 544; }
  const int kc = f >> 3, ot = f & 7;
  const int of = ot * 32 + (l & 31);      // A row = l&31
  const int kb = kc * 16 + (l >> 5) * 8;  // A k = (l>>5)*8 + i
  union { half8 h; uint4 u; } hv, lv;
#pragma unroll
  for (int i = 0; i < 8; ++i) {
    const int k = kb + i;
    const float w = (k < Ksrc) ? W[k * 256 + of] : 0.f;  // zero-pad K tail
    const _Float16 h = (_Float16)w;
    hv.h[i] = h;
    lv.h[i] = (_Float16)((w - (float)h) * SPLIT_S);
  }
  ((uint4*)g_Wh)[bid * 64 + l] = hv.u;
  ((uint4*)g_Wl)[bid * 64 + l] = lv.u;
}

__device__ __forceinline__ half8 as_half8(uint4 u) {
  union { uint4 u4; half8 h; } c; c.u4 = u; return c.h;
}
__device__ __forceinline__ f32x16 mfma32(half8 a, half8 b, f32x16 c) {
  return __builtin_amdgcn_mfma_f32_32x32x16_f16(a, b, c, 0, 0, 0);
}
__device__ __forceinline__ uint32_t h2bits(fp16x2 h) {
  union { fp16x2 h2; uint32_t u; } c; c.h2 = h; return c.u;
}

struct PK { uint2 hi, lo; };
// RTZ split-pack of 4 f32 -> 4 f16-hi + 4 f16-lo (residual * 2048).
__device__ __forceinline__ PK split4(float v0, float v1, float v2, float v3) {
  fp16x2 h01 = __builtin_amdgcn_cvt_pkrtz(v0, v1);
  fp16x2 h23 = __builtin_amdgcn_cvt_pkrtz(v2, v3);
  fp16x2 l01 = __builtin_amdgcn_cvt_pkrtz((v0 - (float)h01[0]) * SPLIT_S,
                                          (v1 - (float)h01[1]) * SPLIT_S);
  fp16x2 l23 = __builtin_amdgcn_cvt_pkrtz((v2 - (float)h23[0]) * SPLIT_S,
                                          (v3 - (float)h23[1]) * SPLIT_S);
  PK r;
  r.hi = make_uint2(h2bits(h01), h2bits(h23));
  r.lo = make_uint2(h2bits(l01), h2bits(l23));
  return r;
}
__device__ __forceinline__ void split1(float v, _Float16& h, _Float16& l) {
  h = (_Float16)v;
  l = (_Float16)((v - (float)h) * SPLIT_S);
}

// Chunk weights: kk=0/1 (K halves of 32-chunk), hi/lo planes.
struct W4 { uint4 h0, l0, h1, l1; };
// WhL/WlL are per-lane bases (+ layer offset). frag base for chunk c = 16c+wu.
__device__ __forceinline__ W4 ldw(const uint4* __restrict__ Wh,
                                  const uint4* __restrict__ Wl, int fb) {
  W4 w;
  w.h0 = Wh[fb * 64];
  w.l0 = Wl[fb * 64];
  w.h1 = Wh[(fb + 8) * 64];
  w.l1 = Wl[(fb + 8) * 64];
  return w;
}

// One K-chunk of 32: 8 ds_read_b128 + 12 MFMA(32x32x16).
__device__ __forceinline__ void body32(f32x16& a10, f32x16& a11,
                                       f32x16& a20, f32x16& a21,
                                       const _Float16* __restrict__ Xp0,
                                       const _Float16* __restrict__ Xp1,
                                       int coff, const W4& w) {
#pragma unroll
  for (int kk = 0; kk < 2; ++kk) {
    const half8 wh = as_half8(kk ? w.h1 : w.h0);
    const half8 wl = as_half8(kk ? w.l1 : w.l0);
    const int o = coff + kk * 16;
    half8 bh0 = *(const half8*)(Xp0 + o);
    half8 bl0 = *(const half8*)(Xp0 + o + 288);
    a10 = mfma32(wh, bh0, a10);
    a20 = mfma32(wh, bl0, a20);
    a20 = mfma32(wl, bh0, a20);
    half8 bh1 = *(const half8*)(Xp1 + o);
    half8 bl1 = *(const half8*)(Xp1 + o + 288);
    a11 = mfma32(wh, bh1, a11);
    a21 = mfma32(wh, bl1, a21);
    a21 = mfma32(wl, bh1, a21);
  }
}

// GEMM over CHUNKS K-chunks with 2-deep weight prefetch (named bufs -> static).
template <int CHUNKS>
__device__ __forceinline__ void lgemm32(f32x16& a10, f32x16& a11,
                                        f32x16& a20, f32x16& a21,
                                        const _Float16* __restrict__ Xp0,
                                        const _Float16* __restrict__ Xp1,
                                        const uint4* __restrict__ Wh,
                                        const uint4* __restrict__ Wl, int wu) {
  W4 A = ldw(Wh, Wl, wu);  // chunk 0
  W4 B;
#pragma unroll 1
  for (int c = 0; c + 2 <= CHUNKS; c += 2) {
    B = ldw(Wh, Wl, 16 * (c + 1) + wu);
    body32(a10, a11, a20, a21, Xp0, Xp1, c * 32, A);
    if (c + 2 < CHUNKS) A = ldw(Wh, Wl, 16 * (c + 2) + wu);
    body32(a10, a11, a20, a21, Xp0, Xp1, (c + 1) * 32, B);
  }
  if (CHUNKS & 1) body32(a10, a11, a20, a21, Xp0, Xp1, (CHUNKS - 1) * 32, A);
}

__device__ __forceinline__ void zero2(f32x16& a, f32x16& b) {
#pragma unroll
  for (int i = 0; i < 16; ++i) { a[i] = 0.f; b[i] = 0.f; }
}

// relu(a1 + a2/2048 + bias) split-packed into X planes.
// Lane holds: sample col = l&31 (per sf), of = 32wu + 8q + 4hi + j (r=4q+j).
__device__ __forceinline__ void epi_write(const f32x16 a1[2], const f32x16 a2[2],
                                          const float* __restrict__ bias,
                                          _Float16* __restrict__ Xs,
                                          int wu, int col, int hi) {
#pragma unroll
  for (int sf = 0; sf < 2; ++sf) {
    _Float16* yrow = Xs + (32 * sf + col) * RSTR;
#pragma unroll
    for (int q = 0; q < 4; ++q) {
      const int ofb = 32 * wu + 8 * q + 4 * hi;
      const float4 bv = *(const float4*)(bias + ofb);
      const float v0 = fmaxf(fmaf(a2[sf][4*q+0], SPLIT_INV, a1[sf][4*q+0]) + bv.x, 0.f);
      const float v1 = fmaxf(fmaf(a2[sf][4*q+1], SPLIT_INV, a1[sf][4*q+1]) + bv.y, 0.f);
      const float v2 = fmaxf(fmaf(a2[sf][4*q+2], SPLIT_INV, a1[sf][4*q+2]) + bv.z, 0.f);
      const float v3 = fmaxf(fmaf(a2[sf][4*q+3], SPLIT_INV, a1[sf][4*q+3]) + bv.w, 0.f);
      const PK p = split4(v0, v1, v2, v3);
      *(uint2*)(yrow + ofb) = p.hi;
      *(uint2*)(yrow + 288 + ofb) = p.lo;
    }
  }
}

// M1 epilogue -> coalesced park in global (wave-private slot, 8 uint4/lane).
// slot[sf*2+qq] = hi of q=2qq (.xy) and q=2qq+1 (.zw); slot[4+..] = lo.
__device__ __forceinline__ void epi_park(const f32x16 a1[2], const f32x16 a2[2],
                                         const float* __restrict__ bias,
                                         uint4* __restrict__ slot,
                                         int wu, int hi, int l) {
#pragma unroll
  for (int sf = 0; sf < 2; ++sf)
#pragma unroll
    for (int qq = 0; qq < 2; ++qq) {
      PK p[2];
#pragma unroll
      for (int h = 0; h < 2; ++h) {
        const int q = 2 * qq + h;
        const int ofb = 32 * wu + 8 * q + 4 * hi;
        const float4 bv = *(const float4*)(bias + ofb);
        const float v0 = fmaxf(fmaf(a2[sf][4*q+0], SPLIT_INV, a1[sf][4*q+0]) + bv.x, 0.f);
        const float v1 = fmaxf(fmaf(a2[sf][4*q+1], SPLIT_INV, a1[sf][4*q+1]) + bv.y, 0.f);
        const float v2 = fmaxf(fmaf(a2[sf][4*q+2], SPLIT_INV, a1[sf][4*q+2]) + bv.z, 0.f);
        const float v3 = fmaxf(fmaf(a2[sf][4*q+3], SPLIT_INV, a1[sf][4*q+3]) + bv.w, 0.f);
        p[h] = split4(v0, v1, v2, v3);
      }
      slot[(sf * 2 + qq) * 64 + l]     = make_uint4(p[0].hi.x, p[0].hi.y, p[1].hi.x, p[1].hi.y);
      slot[(4 + sf * 2 + qq) * 64 + l] = make_uint4(p[0].lo.x, p[0].lo.y, p[1].lo.x, p[1].lo.y);
    }
}

// unpark loaded uint4s -> X planes (mirror of epi_write positions).
__device__ __forceinline__ void unpark_write(const uint4 pk[8],
                                             _Float16* __restrict__ Xs,
                                             int wu, int col, int hi) {
#pragma unroll
  for (int sf = 0; sf < 2; ++sf) {
    _Float16* yrow = Xs + (32 * sf + col) * RSTR;
#pragma unroll
    for (int qq = 0; qq < 2; ++qq) {
      const uint4 h4 = pk[sf * 2 + qq];
      const uint4 l4 = pk[4 + sf * 2 + qq];
      const int ofb0 = 32 * wu + 8 * (2 * qq) + 4 * hi;
      const int ofb1 = ofb0 + 8;
      *(uint2*)(yrow + ofb0) = make_uint2(h4.x, h4.y);
      *(uint2*)(yrow + 288 + ofb0) = make_uint2(l4.x, l4.y);
      *(uint2*)(yrow + ofb1) = make_uint2(h4.z, h4.w);
      *(uint2*)(yrow + 288 + ofb1) = make_uint2(l4.z, l4.w);
    }
  }
}

__global__ __launch_bounds__(512, 4) void topdown_mfma(
    const float* __restrict__ towers, const float* __restrict__ aggregate,
    const float* __restrict__ O1b, const float* __restrict__ O2b,
    const float* __restrict__ O3w, const float* __restrict__ O3b,
    const float* __restrict__ M1b, const float* __restrict__ M2b,
    const float* __restrict__ M3b, float* __restrict__ out) {
  __shared__ __align__(16) _Float16 Xs[64 * RSTR];  // 74752 B
  __shared__ __align__(16) float scr[64][8];        // 2 KB cross-wave reduce
  const int t = threadIdx.x, l = t & 63;
  const int wu = __builtin_amdgcn_readfirstlane(t >> 6);  // wave id = of-eighth
  const int col = l & 31, hi = l >> 5;
  const int n0 = blockIdx.x * 64;
  uint4* park = g_park + ((size_t)blockIdx.x * 8 + (size_t)wu) * (8 * 64);

  // per-lane B-read bases: rows col (sf=0) and 32+col (sf=1), k-offset hi*8
  const _Float16* Xp0 = Xs + col * RSTR + hi * 8;
  const _Float16* Xp1 = Xs + (32 + col) * RSTR + hi * 8;

  // init X: logical features 0..255 = aggregate, 256..287 = 0 (both planes).
  for (int idx = t; idx < 64 * 288; idx += 512) {
    const int ss = idx / 288, f = idx - ss * 288;
    const float v = (f < 256) ? aggregate[f] : 0.f;
    _Float16 h, lo; split1(v, h, lo);
    Xs[ss * RSTR + f] = h;
    Xs[ss * RSTR + 288 + f] = lo;
  }

  float prod = 1.f;
  const float o3bias = O3b[0];
  f32x16 a1[2], a2[2];

  const uint4* WhL = (const uint4*)g_Wh + l;
  const uint4* WlL = (const uint4*)g_Wl + l;

  for (int kk = 0; kk < KS; ++kk) {
    const int tbase = (KS - 1 - kk) * 14;  // reference flips along K
    // tower slice -> logical features 256..269 (both planes)
    for (int idx = t; idx < 64 * 14; idx += 512) {
      const int ss = idx / 14, f = idx - ss * 14;
      const float v = towers[(size_t)(n0 + ss) * (KS * 14) + tbase + f];
      _Float16 h, lo; split1(v, h, lo);
      Xs[ss * RSTR + 256 + f] = h;
      Xs[ss * RSTR + 288 + 256 + f] = lo;
    }
    __syncthreads();  // (a) towers + previous A' visible

    // ---- M1 over X=[A,T]; result -> global park
    zero2(a1[0], a2[0]); zero2(a1[1], a2[1]);
    lgemm32<9>(a1[0], a1[1], a2[0], a2[1], Xp0, Xp1, WhL + 144 * 64, WlL + 144 * 64, wu);
    epi_park(a1, a2, M1b, park, wu, hi, l);

    // ---- O1 over X
    zero2(a1[0], a2[0]); zero2(a1[1], a2[1]);
    lgemm32<9>(a1[0], a1[1], a2[0], a2[1], Xp0, Xp1, WhL, WlL, wu);
    __syncthreads();  // (b) all X reads done; park stores in flight
    epi_write(a1, a2, O1b, Xs, wu, col, hi);  // X[0..255] <- h1
    __syncthreads();  // (c) h1 visible

    // ---- O2 over h1
    zero2(a1[0], a2[0]); zero2(a1[1], a2[1]);
    lgemm32<8>(a1[0], a1[1], a2[0], a2[1], Xp0, Xp1, WhL + 288 * 64, WlL + 288 * 64, wu);

    // unpark loads issued now (wave-private; latency hides under O3 tail)
    asm volatile("" ::: "memory");
    uint4 pk[8];
#pragma unroll
    for (int q = 0; q < 8; ++q) pk[q] = park[q * 64 + l];

    // O3 tail: relu(O2) dot O3w over this wave's 32 of -> per-sample partials
    float tp[2] = {0.f, 0.f};
#pragma unroll
    for (int sf = 0; sf < 2; ++sf)
#pragma unroll
      for (int q = 0; q < 4; ++q) {
        const int ofb = 32 * wu + 8 * q + 4 * hi;
        const float4 bv = *(const float4*)(O2b + ofb);
        const float4 ov = *(const float4*)(O3w + ofb);
        tp[sf] += fmaxf(fmaf(a2[sf][4*q+0], SPLIT_INV, a1[sf][4*q+0]) + bv.x, 0.f) * ov.x;
        tp[sf] += fmaxf(fmaf(a2[sf][4*q+1], SPLIT_INV, a1[sf][4*q+1]) + bv.y, 0.f) * ov.y;
        tp[sf] += fmaxf(fmaf(a2[sf][4*q+2], SPLIT_INV, a1[sf][4*q+2]) + bv.z, 0.f) * ov.z;
        tp[sf] += fmaxf(fmaf(a2[sf][4*q+3], SPLIT_INV, a1[sf][4*q+3]) + bv.w, 0.f) * ov.w;
      }
    tp[0] += __shfl_xor(tp[0], 32);  // combine hi-halves (rows 0..15 + 16..31)
    tp[1] += __shfl_xor(tp[1], 32);
    if (hi == 0) {
      scr[col][wu] = tp[0];
      scr[32 + col][wu] = tp[1];
    }
    __syncthreads();  // (d) scr ready; all h1 reads done

    unpark_write(pk, Xs, wu, col, hi);  // X <- A' (M1 result)
    if (t < 64) {
      const float4 s0 = *(const float4*)(scr[t]);
      const float4 s1 = *(const float4*)(scr[t] + 4);
      const float tt = ((s0.x + s0.y) + (s0.z + s0.w)) +
                       ((s1.x + s1.y) + (s1.z + s1.w)) + o3bias;
      prod *= 1.f / (1.f + expf(-tt));
    }
    __syncthreads();  // (e) A' visible

    // ---- M2 (in place)
    zero2(a1[0], a2[0]); zero2(a1[1], a2[1]);
    lgemm32<8>(a1[0], a1[1], a2[0], a2[1], Xp0, Xp1, WhL + 416 * 64, WlL + 416 * 64, wu);
    __syncthreads();  // (f) reads done
    epi_write(a1, a2, M2b, Xs, wu, col, hi);
    __syncthreads();  // (g)

    // ---- M3 (in place); next-iter sync (a) covers the write->read edge
    zero2(a1[0], a2[0]); zero2(a1[1], a2[1]);
    lgemm32<8>(a1[0], a1[1], a2[0], a2[1], Xp0, Xp1, WhL + 544 * 64, WlL + 544 * 64, wu);
    __syncthreads();  // (h) reads done
    epi_write(a1, a2, M3b, Xs, wu, col, hi);
  }

  if (t < 64) out[n0 + t] = prod;
}

extern "C" void kernel_launch(void* const* d_in, const int* in_sizes, int n_in,
                              void* d_out, int out_size, void* d_ws, size_t ws_size,
                              hipStream_t stream) {
  const float* towers    = (const float*)d_in[0];
  const float* aggregate = (const float*)d_in[1];
  const float* M1w = (const float*)d_in[2];
  const float* M1b = (const float*)d_in[3];
  const float* M2w = (const float*)d_in[4];
  const float* M2b = (const float*)d_in[5];
  const float* M3w = (const float*)d_in[6];
  const float* M3b = (const float*)d_in[7];
  const float* O1w = (const float*)d_in[8];
  const float* O1b = (const float*)d_in[9];
  const float* O2w = (const float*)d_in[10];
  const float* O2b = (const float*)d_in[11];
  const float* O3w = (const float*)d_in[12];
  const float* O3b = (const float*)d_in[13];
  float* out = (float*)d_out;

  prep_w<<<672, 64, 0, stream>>>(O1w, M1w, O2w, M2w, M3w);

  const int nblocks = out_size / 64;  // 2048 blocks x 512 threads (8 waves)
  topdown_mfma<<<nblocks, 512, 0, stream>>>(towers, aggregate, O1b, O2b, O3w,
                                            O3b, M1b, M2b, M3b, out);
}